// Round 7
// baseline (29322.171 us; speedup 1.0000x reference)
//
#include <hip/hip_runtime.h>
#include <stdint.h>

// RK4 ODE integrator: dx/dt = W2·tanh(W1·x + b1) + b2, 64 steps, t in [0,1].
// B=4096, D=1024, H=4096. bf16 MFMA 16x16x32, fp32 accumulate.
// Both GEMMs: explicit LDS double-buffer, raw s_barrier + fine s_waitcnt
// vmcnt(N) (AITER-style: prefetch loads stay in flight across the barrier;
// never vmcnt(0) mid-loop). R6 verified -1.8 ms on GEMM2; now on GEMM1 too.
// GEMM1: h = tanh(x@W1^T + b1), TM=128/TN=128/BK=32, 1024 blocks, vmcnt(4).
// GEMM2: k = h@W2^T + b2 + fused RK4 epilogue, TM=128/TN=64/BK=64, vmcnt(6).
// R4/R5 lesson: split-K cross-block combine (__threadfence) -> 80 ms. Dead.

typedef __attribute__((ext_vector_type(8))) __bf16 bf16x8;
typedef __attribute__((ext_vector_type(4))) float floatx4;

#define TM 128

__device__ __forceinline__ unsigned short f2bf(float f) {
  union { float f; unsigned u; } v; v.f = f;
  unsigned r = v.u + 0x7fffu + ((v.u >> 16) & 1u);  // RNE
  return (unsigned short)(r >> 16);
}

__device__ __forceinline__ float tanh_fast(float x) {
  float cx = fminf(15.0f, fmaxf(-15.0f, x));
  float e = __expf(2.0f * cx);                       // v_exp_f32
  return fmaf(-2.0f, __builtin_amdgcn_rcpf(e + 1.0f), 1.0f);
}

__device__ __forceinline__ void async16(const unsigned short* g, unsigned short* l) {
  // direct global->LDS, 16B/lane; LDS dest = wave-uniform base + lane*16
  __builtin_amdgcn_global_load_lds(
      (__attribute__((address_space(1))) void*)(g),
      (__attribute__((address_space(3))) void*)(l),
      16, 0, 0);
}

// -------- GEMM1: h = tanh(x@W1^T + b1), double-buffered, vmcnt(4) -----------
__global__ __launch_bounds__(256, 2) void gemm1(
    const unsigned short* __restrict__ A,   // [M,K] bf16
    const unsigned short* __restrict__ Bw,  // [N,K] bf16 (B^T form)
    const float* __restrict__ bias, int K, int N,
    unsigned short* __restrict__ hOut) {
  constexpr int BKT = 32;
  __shared__ unsigned short As[2][TM * BKT];   // 2 x 8 KB
  __shared__ unsigned short Bs[2][TM * BKT];   // 2 x 8 KB

  const int tid  = threadIdx.x;
  const int lane = tid & 63;
  const int wv   = tid >> 6;
  const int bm   = blockIdx.y * TM;
  const int bn   = blockIdx.x * TM;

  const int wm   = (wv >> 1) * 64;
  const int wn   = (wv & 1) * 64;
  const int lrow = lane & 15;
  const int lk   = lane >> 4;

  floatx4 acc[4][4];
#pragma unroll
  for (int i = 0; i < 4; ++i)
#pragma unroll
    for (int j = 0; j < 4; ++j) acc[i][j] = (floatx4){0.f, 0.f, 0.f, 0.f};

  const int sr  = lane >> 2;          // 16 rows x 32 cols per call
  const int sc  = (lane & 3) << 3;
  const int arb = wv * 32;

  const unsigned short* pA = A  + (size_t)(bm + arb + sr) * K + sc;
  const unsigned short* pB = Bw + (size_t)(bn + arb + sr) * K + sc;
  const size_t rstep = (size_t)16 * K;

  const int nIter = K / BKT;            // 32

#define STAGE1(buf)                                          \
  do {                                                       \
    async16(pA,         &As[buf][(arb)      * BKT]);         \
    async16(pA + rstep, &As[buf][(arb + 16) * BKT]);         \
    async16(pB,         &Bs[buf][(arb)      * BKT]);         \
    async16(pB + rstep, &Bs[buf][(arb + 16) * BKT]);         \
    pA += BKT; pB += BKT;                                    \
  } while (0)

  STAGE1(0);                            // prologue
  for (int i = 0; i < nIter; ++i) {
    const int cur = i & 1;
    if (i + 1 < nIter) {
      STAGE1(!cur);                     // prefetch next tile
      asm volatile("s_waitcnt vmcnt(4)" ::: "memory");  // tile i done; next in flight
    } else {
      asm volatile("s_waitcnt vmcnt(0)" ::: "memory");
    }
    asm volatile("s_barrier" ::: "memory");

    bf16x8 aF[4], bF[4];
#pragma unroll
    for (int ii = 0; ii < 4; ++ii)
      aF[ii] = *(const bf16x8*)(&As[cur][(wm + ii * 16 + lrow) * BKT + lk * 8]);
#pragma unroll
    for (int j = 0; j < 4; ++j)
      bF[j] = *(const bf16x8*)(&Bs[cur][(wn + j * 16 + lrow) * BKT + lk * 8]);
#pragma unroll
    for (int ii = 0; ii < 4; ++ii)
#pragma unroll
      for (int j = 0; j < 4; ++j)
        acc[ii][j] = __builtin_amdgcn_mfma_f32_16x16x32_bf16(aF[ii], bF[j], acc[ii][j], 0, 0, 0);
    asm volatile("s_barrier" ::: "memory");   // all waves done reading cur
  }
#undef STAGE1

  // C/D layout: col = lane&15, row = (lane>>4)*4 + r (m89-verified)
#pragma unroll
  for (int j = 0; j < 4; ++j) {
    const int col = bn + wn + j * 16 + lrow;
    const float bcol = bias[col];
#pragma unroll
    for (int i = 0; i < 4; ++i) {
      const int row0 = bm + wm + i * 16 + lk * 4;
#pragma unroll
      for (int r = 0; r < 4; ++r)
        hOut[(size_t)(row0 + r) * N + col] = f2bf(tanh_fast(acc[i][j][r] + bcol));
    }
  }
}

// ------- GEMM2: k = h@W2^T + b2, double-buffered LDS, fused RK4 epilogue -----
// EPI: 1 = first (xacc = xf + aacc*k ; xb = bf16(xf + cnext*k))
//      2 = mid   (xacc += aacc*k    ; xb = bf16(xf + cnext*k))
//      3 = last  (xf = xacc + aacc*k; xb = bf16(xf))
template <int EPI>
__global__ __launch_bounds__(256, 2) void gemm2_db(
    const unsigned short* __restrict__ A,   // [M,K] bf16 (h)
    const unsigned short* __restrict__ Bw,  // [N,K] bf16 (W2, B^T form)
    const float* __restrict__ bias, int K, int N,
    const float* xf_in, float* xacc, float* xf_out, unsigned short* xb,
    float aacc, float cnext) {
  constexpr int TN = 64, BKT = 64;
  __shared__ unsigned short As[2][TM * BKT];   // 2 x 16 KB
  __shared__ unsigned short Bs[2][TN * BKT];   // 2 x 8 KB

  const int tid  = threadIdx.x;
  const int lane = tid & 63;
  const int wv   = tid >> 6;
  const int bm   = blockIdx.y * TM;
  const int bn   = blockIdx.x * TN;

  const int wm   = (wv >> 1) * 64;
  const int wn   = (wv & 1) * 32;
  const int lrow = lane & 15;
  const int lk   = lane >> 4;

  floatx4 acc[4][2];
#pragma unroll
  for (int i = 0; i < 4; ++i)
#pragma unroll
    for (int j = 0; j < 2; ++j) acc[i][j] = (floatx4){0.f, 0.f, 0.f, 0.f};

  // staging: 8 rows x 64 cols per async16 call; A 4 calls, B 2 calls per wave
  const int sr  = lane >> 3;
  const int sc  = (lane & 7) << 3;
  const int arb = wv * 32;
  const int brb = wv * 16;

  const unsigned short* pA = A  + (size_t)(bm + arb + sr) * K + sc;
  const unsigned short* pB = Bw + (size_t)(bn + brb + sr) * K + sc;

  const int nIter = K / BKT;            // 64

#define STAGE2(buf)                                                       \
  do {                                                                    \
    _Pragma("unroll")                                                     \
    for (int c = 0; c < 4; ++c)                                           \
      async16(pA + (size_t)(c * 8) * K, &As[buf][(arb + c * 8) * BKT]);   \
    _Pragma("unroll")                                                     \
    for (int c = 0; c < 2; ++c)                                           \
      async16(pB + (size_t)(c * 8) * K, &Bs[buf][(brb + c * 8) * BKT]);   \
    pA += BKT; pB += BKT;                                                 \
  } while (0)

  STAGE2(0);                            // prologue
  for (int i = 0; i < nIter; ++i) {
    const int cur = i & 1;
    if (i + 1 < nIter) {
      STAGE2(!cur);                     // prefetch next tile into other buffer
      asm volatile("s_waitcnt vmcnt(6)" ::: "memory");  // tile i done; next in flight
    } else {
      asm volatile("s_waitcnt vmcnt(0)" ::: "memory");
    }
    asm volatile("s_barrier" ::: "memory");

#pragma unroll
    for (int kh = 0; kh < 2; ++kh) {
      bf16x8 aF[4], bF[2];
#pragma unroll
      for (int ii = 0; ii < 4; ++ii)
        aF[ii] = *(const bf16x8*)(&As[cur][(wm + ii * 16 + lrow) * BKT + kh * 32 + lk * 8]);
#pragma unroll
      for (int j = 0; j < 2; ++j)
        bF[j] = *(const bf16x8*)(&Bs[cur][(wn + j * 16 + lrow) * BKT + kh * 32 + lk * 8]);
#pragma unroll
      for (int ii = 0; ii < 4; ++ii)
#pragma unroll
        for (int j = 0; j < 2; ++j)
          acc[ii][j] = __builtin_amdgcn_mfma_f32_16x16x32_bf16(aF[ii], bF[j], acc[ii][j], 0, 0, 0);
    }
    asm volatile("s_barrier" ::: "memory");   // all waves done reading cur
  }
#undef STAGE2

  // epilogue — C/D layout: col = lane&15, row = (lane>>4)*4 + r
#pragma unroll
  for (int j = 0; j < 2; ++j) {
    const int col = bn + wn + j * 16 + lrow;
    const float bcol = bias[col];
#pragma unroll
    for (int i = 0; i < 4; ++i) {
      const int row0 = bm + wm + i * 16 + lk * 4;
#pragma unroll
      for (int r = 0; r < 4; ++r) {
        const float v = acc[i][j][r] + bcol;
        const size_t idx = (size_t)(row0 + r) * N + col;
        if constexpr (EPI == 1) {
          const float xv = xf_in[idx];
          xacc[idx] = fmaf(aacc, v, xv);
          xb[idx] = f2bf(fmaf(cnext, v, xv));
        } else if constexpr (EPI == 2) {
          const float xv = xf_in[idx];
          xacc[idx] = fmaf(aacc, v, xacc[idx]);
          xb[idx] = f2bf(fmaf(cnext, v, xv));
        } else {
          const float xn = fmaf(aacc, v, xacc[idx]);
          xf_out[idx] = xn;
          xb[idx] = f2bf(xn);
        }
      }
    }
  }
}

__global__ void cvt_kernel(const float* __restrict__ s, unsigned short* __restrict__ d, int n4) {
  int i = blockIdx.x * 256 + threadIdx.x;
  if (i < n4) {
    float4 v = ((const float4*)s)[i];
    ((ushort4*)d)[i] = make_ushort4(f2bf(v.x), f2bf(v.y), f2bf(v.z), f2bf(v.w));
  }
}

__global__ void initx_kernel(const float* __restrict__ s, float* __restrict__ xf,
                             unsigned short* __restrict__ xb, int n4) {
  int i = blockIdx.x * 256 + threadIdx.x;
  if (i < n4) {
    float4 v = ((const float4*)s)[i];
    ((float4*)xf)[i] = v;
    ((ushort4*)xb)[i] = make_ushort4(f2bf(v.x), f2bf(v.y), f2bf(v.z), f2bf(v.w));
  }
}

extern "C" void kernel_launch(void* const* d_in, const int* in_sizes, int n_in,
                              void* d_out, int out_size, void* d_ws, size_t ws_size,
                              hipStream_t stream) {
  const float* x  = (const float*)d_in[0];
  const float* W1 = (const float*)d_in[1];
  const float* b1 = (const float*)d_in[2];
  const float* W2 = (const float*)d_in[3];
  const float* b2 = (const float*)d_in[4];
  const int H = in_sizes[2];            // 4096
  const int D = in_sizes[4];            // 1024
  const int B = in_sizes[0] / D;        // 4096

  // workspace layout (~72 MB): W1b | W2b | xb | hb | xacc
  unsigned short* W1b = (unsigned short*)d_ws;
  unsigned short* W2b = W1b + (size_t)H * D;
  unsigned short* xb  = W2b + (size_t)D * H;
  unsigned short* hb  = xb + (size_t)B * D;
  float* xacc = (float*)(hb + (size_t)B * H);
  float* xf   = (float*)d_out;          // fp32 state lives in d_out

  const float dt = 1.0f / 64.0f;

  int n4 = (H * D) / 4;
  cvt_kernel<<<dim3((n4 + 255) / 256), dim3(256), 0, stream>>>(W1, W1b, n4);
  cvt_kernel<<<dim3((n4 + 255) / 256), dim3(256), 0, stream>>>(W2, W2b, n4);
  int m4 = (B * D) / 4;
  initx_kernel<<<dim3((m4 + 255) / 256), dim3(256), 0, stream>>>(x, xf, xb, m4);

  dim3 blk(256, 1, 1);
  dim3 g1(H / 128, B / TM, 1);          // 32 x 32
  dim3 g2(D / 64,  B / TM, 1);          // 16 x 32

  for (int s = 0; s < 64; ++s) {
    // k1
    gemm1<<<g1, blk, 0, stream>>>(xb, W1b, b1, D, H, hb);
    gemm2_db<1><<<g2, blk, 0, stream>>>(hb, W2b, b2, H, D, xf, xacc, xf, xb, dt / 6.f, dt / 2.f);
    // k2
    gemm1<<<g1, blk, 0, stream>>>(xb, W1b, b1, D, H, hb);
    gemm2_db<2><<<g2, blk, 0, stream>>>(hb, W2b, b2, H, D, xf, xacc, xf, xb, dt / 3.f, dt / 2.f);
    // k3
    gemm1<<<g1, blk, 0, stream>>>(xb, W1b, b1, D, H, hb);
    gemm2_db<2><<<g2, blk, 0, stream>>>(hb, W2b, b2, H, D, xf, xacc, xf, xb, dt / 3.f, dt);
    // k4
    gemm1<<<g1, blk, 0, stream>>>(xb, W1b, b1, D, H, hb);
    gemm2_db<3><<<g2, blk, 0, stream>>>(hb, W2b, b2, H, D, xf, xacc, xf, xb, dt / 6.f, 0.f);
  }
}

// Round 8
// 28065.698 us; speedup vs baseline: 1.0448x; 1.0448x over previous
//
#include <hip/hip_runtime.h>
#include <stdint.h>

// RK4 ODE integrator: dx/dt = W2·tanh(W1·x + b1) + b2, 64 steps, t in [0,1].
// B=4096, D=1024, H=4096. bf16 MFMA 16x16x32, fp32 accumulate.
// GEMM1: h = tanh(x@W1^T + b1), TM=128/TN=128/BK=32, single-buffered m97
//        structure (3 blk/CU hides the drain; R7 showed explicit dbuf
//        REGRESSES here — m139 replicated).
// GEMM2: k = h@W2^T + b2 + fused RK4 epilogue. TM=128/TN=64/BK=64, 512
//        blocks (2 blk/CU) -> R6 AITER-style dbuf + vmcnt(6) (verified -1.8
//        ms) + NEW: XCD-clustering block swizzle (by = id%32) so all 16
//        blocks sharing one 1 MB A-strip land on one XCD's L2 (A traffic
//        ~256 MB -> ~32 MB per dispatch).
// R4/R5 lesson: split-K cross-block combine (__threadfence) -> 80 ms. Dead.

typedef __attribute__((ext_vector_type(8))) __bf16 bf16x8;
typedef __attribute__((ext_vector_type(4))) float floatx4;

#define TM 128

__device__ __forceinline__ unsigned short f2bf(float f) {
  union { float f; unsigned u; } v; v.f = f;
  unsigned r = v.u + 0x7fffu + ((v.u >> 16) & 1u);  // RNE
  return (unsigned short)(r >> 16);
}

__device__ __forceinline__ float tanh_fast(float x) {
  float cx = fminf(15.0f, fmaxf(-15.0f, x));
  float e = __expf(2.0f * cx);                       // v_exp_f32
  return fmaf(-2.0f, __builtin_amdgcn_rcpf(e + 1.0f), 1.0f);
}

__device__ __forceinline__ void async16(const unsigned short* g, unsigned short* l) {
  // direct global->LDS, 16B/lane; LDS dest = wave-uniform base + lane*16
  __builtin_amdgcn_global_load_lds(
      (__attribute__((address_space(1))) void*)(g),
      (__attribute__((address_space(3))) void*)(l),
      16, 0, 0);
}

// -------- GEMM1: h = tanh(x@W1^T + b1), single-buffered m97 (R6 form) -------
__global__ __launch_bounds__(256, 2) void gemm1(
    const unsigned short* __restrict__ A,   // [M,K] bf16
    const unsigned short* __restrict__ Bw,  // [N,K] bf16 (B^T form)
    const float* __restrict__ bias, int K, int N,
    unsigned short* __restrict__ hOut) {
  constexpr int BKT = 32;
  __shared__ unsigned short As[TM * BKT];
  __shared__ unsigned short Bs[TM * BKT];

  const int tid  = threadIdx.x;
  const int lane = tid & 63;
  const int wv   = tid >> 6;
  const int bm   = blockIdx.y * TM;
  const int bn   = blockIdx.x * TM;

  const int wm   = (wv >> 1) * 64;
  const int wn   = (wv & 1) * 64;
  const int lrow = lane & 15;
  const int lk   = lane >> 4;

  floatx4 acc[4][4];
#pragma unroll
  for (int i = 0; i < 4; ++i)
#pragma unroll
    for (int j = 0; j < 4; ++j) acc[i][j] = (floatx4){0.f, 0.f, 0.f, 0.f};

  const int sr  = lane >> 2;          // 16 rows x 32 cols per call
  const int sc  = (lane & 3) << 3;
  const int arb = wv * 32;

  const unsigned short* pA = A  + (size_t)(bm + arb + sr) * K + sc;
  const unsigned short* pB = Bw + (size_t)(bn + arb + sr) * K + sc;
  const size_t rstep = (size_t)16 * K;

  for (int k0 = 0; k0 < K; k0 += BKT) {
    async16(pA, &As[arb * BKT]);
    async16(pA + rstep, &As[(arb + 16) * BKT]);
    async16(pB, &Bs[arb * BKT]);
    async16(pB + rstep, &Bs[(arb + 16) * BKT]);
    pA += BKT; pB += BKT;
    asm volatile("s_waitcnt vmcnt(0)" ::: "memory");
    __syncthreads();

    bf16x8 aF[4], bF[4];
#pragma unroll
    for (int i = 0; i < 4; ++i)
      aF[i] = *(const bf16x8*)(&As[(wm + i * 16 + lrow) * BKT + lk * 8]);
#pragma unroll
    for (int j = 0; j < 4; ++j)
      bF[j] = *(const bf16x8*)(&Bs[(wn + j * 16 + lrow) * BKT + lk * 8]);
#pragma unroll
    for (int i = 0; i < 4; ++i)
#pragma unroll
      for (int j = 0; j < 4; ++j)
        acc[i][j] = __builtin_amdgcn_mfma_f32_16x16x32_bf16(aF[i], bF[j], acc[i][j], 0, 0, 0);
    __syncthreads();
  }

  // C/D layout: col = lane&15, row = (lane>>4)*4 + r (m89-verified)
#pragma unroll
  for (int j = 0; j < 4; ++j) {
    const int col = bn + wn + j * 16 + lrow;
    const float bcol = bias[col];
#pragma unroll
    for (int i = 0; i < 4; ++i) {
      const int row0 = bm + wm + i * 16 + lk * 4;
#pragma unroll
      for (int r = 0; r < 4; ++r)
        hOut[(size_t)(row0 + r) * N + col] = f2bf(tanh_fast(acc[i][j][r] + bcol));
    }
  }
}

// ------- GEMM2: k = h@W2^T + b2, dbuf LDS + XCD swizzle, RK4 epilogue -------
// EPI: 1 = first (xacc = xf + aacc*k ; xb = bf16(xf + cnext*k))
//      2 = mid   (xacc += aacc*k    ; xb = bf16(xf + cnext*k))
//      3 = last  (xf = xacc + aacc*k; xb = bf16(xf))
template <int EPI>
__global__ __launch_bounds__(256, 2) void gemm2_db(
    const unsigned short* __restrict__ A,   // [M,K] bf16 (h)
    const unsigned short* __restrict__ Bw,  // [N,K] bf16 (W2, B^T form)
    const float* __restrict__ bias, int K, int N,
    const float* xf_in, float* xacc, float* xf_out, unsigned short* xb,
    float aacc, float cnext) {
  constexpr int TN = 64, BKT = 64;
  __shared__ unsigned short As[2][TM * BKT];   // 2 x 16 KB
  __shared__ unsigned short Bs[2][TN * BKT];   // 2 x 8 KB

  const int tid  = threadIdx.x;
  const int lane = tid & 63;
  const int wv   = tid >> 6;
  // XCD-clustering swizzle: 1-D grid of 512; by = id%32 so the 16 blocks
  // reading the same A-strip share id%8 (= one XCD's L2). A-strip = 1 MB;
  // 4 strips/XCD = 4 MB, fits the XCD L2 exactly.
  const int id = blockIdx.x;
  const int bm = (id & 31) * TM;
  const int bn = (id >> 5) * TN;

  const int wm   = (wv >> 1) * 64;
  const int wn   = (wv & 1) * 32;
  const int lrow = lane & 15;
  const int lk   = lane >> 4;

  floatx4 acc[4][2];
#pragma unroll
  for (int i = 0; i < 4; ++i)
#pragma unroll
    for (int j = 0; j < 2; ++j) acc[i][j] = (floatx4){0.f, 0.f, 0.f, 0.f};

  // staging: 8 rows x 64 cols per async16 call; A 4 calls, B 2 calls per wave
  const int sr  = lane >> 3;
  const int sc  = (lane & 7) << 3;
  const int arb = wv * 32;
  const int brb = wv * 16;

  const unsigned short* pA = A  + (size_t)(bm + arb + sr) * K + sc;
  const unsigned short* pB = Bw + (size_t)(bn + brb + sr) * K + sc;

  const int nIter = K / BKT;            // 64

#define STAGE2(buf)                                                       \
  do {                                                                    \
    _Pragma("unroll")                                                     \
    for (int c = 0; c < 4; ++c)                                           \
      async16(pA + (size_t)(c * 8) * K, &As[buf][(arb + c * 8) * BKT]);   \
    _Pragma("unroll")                                                     \
    for (int c = 0; c < 2; ++c)                                           \
      async16(pB + (size_t)(c * 8) * K, &Bs[buf][(brb + c * 8) * BKT]);   \
    pA += BKT; pB += BKT;                                                 \
  } while (0)

  STAGE2(0);                            // prologue
  for (int i = 0; i < nIter; ++i) {
    const int cur = i & 1;
    if (i + 1 < nIter) {
      STAGE2(!cur);                     // prefetch next tile into other buffer
      asm volatile("s_waitcnt vmcnt(6)" ::: "memory");  // tile i done; next in flight
    } else {
      asm volatile("s_waitcnt vmcnt(0)" ::: "memory");
    }
    asm volatile("s_barrier" ::: "memory");

#pragma unroll
    for (int kh = 0; kh < 2; ++kh) {
      bf16x8 aF[4], bF[2];
#pragma unroll
      for (int ii = 0; ii < 4; ++ii)
        aF[ii] = *(const bf16x8*)(&As[cur][(wm + ii * 16 + lrow) * BKT + kh * 32 + lk * 8]);
#pragma unroll
      for (int j = 0; j < 2; ++j)
        bF[j] = *(const bf16x8*)(&Bs[cur][(wn + j * 16 + lrow) * BKT + kh * 32 + lk * 8]);
#pragma unroll
      for (int ii = 0; ii < 4; ++ii)
#pragma unroll
        for (int j = 0; j < 2; ++j)
          acc[ii][j] = __builtin_amdgcn_mfma_f32_16x16x32_bf16(aF[ii], bF[j], acc[ii][j], 0, 0, 0);
    }
    asm volatile("s_barrier" ::: "memory");   // all waves done reading cur
  }
#undef STAGE2

  // epilogue — C/D layout: col = lane&15, row = (lane>>4)*4 + r
#pragma unroll
  for (int j = 0; j < 2; ++j) {
    const int col = bn + wn + j * 16 + lrow;
    const float bcol = bias[col];
#pragma unroll
    for (int i = 0; i < 4; ++i) {
      const int row0 = bm + wm + i * 16 + lk * 4;
#pragma unroll
      for (int r = 0; r < 4; ++r) {
        const float v = acc[i][j][r] + bcol;
        const size_t idx = (size_t)(row0 + r) * N + col;
        if constexpr (EPI == 1) {
          const float xv = xf_in[idx];
          xacc[idx] = fmaf(aacc, v, xv);
          xb[idx] = f2bf(fmaf(cnext, v, xv));
        } else if constexpr (EPI == 2) {
          const float xv = xf_in[idx];
          xacc[idx] = fmaf(aacc, v, xacc[idx]);
          xb[idx] = f2bf(fmaf(cnext, v, xv));
        } else {
          const float xn = fmaf(aacc, v, xacc[idx]);
          xf_out[idx] = xn;
          xb[idx] = f2bf(xn);
        }
      }
    }
  }
}

__global__ void cvt_kernel(const float* __restrict__ s, unsigned short* __restrict__ d, int n4) {
  int i = blockIdx.x * 256 + threadIdx.x;
  if (i < n4) {
    float4 v = ((const float4*)s)[i];
    ((ushort4*)d)[i] = make_ushort4(f2bf(v.x), f2bf(v.y), f2bf(v.z), f2bf(v.w));
  }
}

__global__ void initx_kernel(const float* __restrict__ s, float* __restrict__ xf,
                             unsigned short* __restrict__ xb, int n4) {
  int i = blockIdx.x * 256 + threadIdx.x;
  if (i < n4) {
    float4 v = ((const float4*)s)[i];
    ((float4*)xf)[i] = v;
    ((ushort4*)xb)[i] = make_ushort4(f2bf(v.x), f2bf(v.y), f2bf(v.z), f2bf(v.w));
  }
}

extern "C" void kernel_launch(void* const* d_in, const int* in_sizes, int n_in,
                              void* d_out, int out_size, void* d_ws, size_t ws_size,
                              hipStream_t stream) {
  const float* x  = (const float*)d_in[0];
  const float* W1 = (const float*)d_in[1];
  const float* b1 = (const float*)d_in[2];
  const float* W2 = (const float*)d_in[3];
  const float* b2 = (const float*)d_in[4];
  const int H = in_sizes[2];            // 4096
  const int D = in_sizes[4];            // 1024
  const int B = in_sizes[0] / D;        // 4096

  // workspace layout (~72 MB): W1b | W2b | xb | hb | xacc
  unsigned short* W1b = (unsigned short*)d_ws;
  unsigned short* W2b = W1b + (size_t)H * D;
  unsigned short* xb  = W2b + (size_t)D * H;
  unsigned short* hb  = xb + (size_t)B * D;
  float* xacc = (float*)(hb + (size_t)B * H);
  float* xf   = (float*)d_out;          // fp32 state lives in d_out

  const float dt = 1.0f / 64.0f;

  int n4 = (H * D) / 4;
  cvt_kernel<<<dim3((n4 + 255) / 256), dim3(256), 0, stream>>>(W1, W1b, n4);
  cvt_kernel<<<dim3((n4 + 255) / 256), dim3(256), 0, stream>>>(W2, W2b, n4);
  int m4 = (B * D) / 4;
  initx_kernel<<<dim3((m4 + 255) / 256), dim3(256), 0, stream>>>(x, xf, xb, m4);

  dim3 blk(256, 1, 1);
  dim3 g1(H / 128, B / TM, 1);          // 32 x 32
  dim3 g2((D / 64) * (B / TM), 1, 1);   // 512 linear, swizzled in-kernel

  for (int s = 0; s < 64; ++s) {
    // k1
    gemm1<<<g1, blk, 0, stream>>>(xb, W1b, b1, D, H, hb);
    gemm2_db<1><<<g2, blk, 0, stream>>>(hb, W2b, b2, H, D, xf, xacc, xf, xb, dt / 6.f, dt / 2.f);
    // k2
    gemm1<<<g1, blk, 0, stream>>>(xb, W1b, b1, D, H, hb);
    gemm2_db<2><<<g2, blk, 0, stream>>>(hb, W2b, b2, H, D, xf, xacc, xf, xb, dt / 3.f, dt / 2.f);
    // k3
    gemm1<<<g1, blk, 0, stream>>>(xb, W1b, b1, D, H, hb);
    gemm2_db<2><<<g2, blk, 0, stream>>>(hb, W2b, b2, H, D, xf, xacc, xf, xb, dt / 3.f, dt);
    // k4
    gemm1<<<g1, blk, 0, stream>>>(xb, W1b, b1, D, H, hb);
    gemm2_db<3><<<g2, blk, 0, stream>>>(hb, W2b, b2, H, D, xf, xacc, xf, xb, dt / 6.f, 0.f);
  }
}